// Round 2
// 275.417 us; speedup vs baseline: 1.0473x; 1.0473x over previous
//
#include <hip/hip_runtime.h>

#define NN   10240
#define EE   320000
#define BGR  64
#define NPG  160
#define KK   16
#define DINF 25
#define DD   256
#define LL   4
#define LNEPS 1e-5f

typedef unsigned short ushort_t;
typedef __attribute__((ext_vector_type(8))) short s8v;
typedef __attribute__((ext_vector_type(4))) float f4v;

__device__ __forceinline__ float bf2f(ushort_t u) {
  union { unsigned u; float f; } a; a.u = ((unsigned)u) << 16; return a.f;
}
__device__ __forceinline__ ushort_t f2bf(float f) {
  union { float f; unsigned u; } a; a.f = f;
  unsigned r = (a.u + 0x7fffu + ((a.u >> 16) & 1u)) >> 16;   // RNE
  return (ushort_t)r;
}

// async global->LDS DMA, 16B per lane, dest = wave-uniform base + lane*16
__device__ __forceinline__ void gld16(const void* g, void* l) {
  __builtin_amdgcn_global_load_lds(
      (const __attribute__((address_space(1))) unsigned int*)g,
      (__attribute__((address_space(3))) unsigned int*)l, 16, 0, 0);
}

// ---------------- block reduce (256 threads = 4 waves) ----------------
__device__ __forceinline__ float2 block_reduce2(float a, float b, float* red) {
  __syncthreads();
  #pragma unroll
  for (int off = 32; off > 0; off >>= 1) {
    a += __shfl_down(a, off);
    b += __shfl_down(b, off);
  }
  int lane = threadIdx.x & 63;
  int wid  = threadIdx.x >> 6;
  if (lane == 0) { red[wid * 2] = a; red[wid * 2 + 1] = b; }
  __syncthreads();
  float sa = red[0] + red[2] + red[4] + red[6];
  float sb = red[1] + red[3] + red[5] + red[7];
  return make_float2(sa, sb);
}

// ---------------- setup (merged): degfid + weight prep + regloss partials ----------------
__global__ __launch_bounds__(256) void setup_kernel(const int* __restrict__ dst,
                                                    const float* __restrict__ s,
                                                    const float* __restrict__ Wi,
                                                    const float* __restrict__ Wo,
                                                    const float* __restrict__ Wi0,
                                                    const float* __restrict__ Wo0,
                                                    const float* __restrict__ b_out0,
                                                    const float* __restrict__ b_out,
                                                    int* __restrict__ deg,
                                                    int* __restrict__ fid,
                                                    ushort_t* __restrict__ BT,
                                                    ushort_t* __restrict__ BT0,
                                                    float* __restrict__ partials) {
  int bid0 = blockIdx.x;
  int t = threadIdx.x;
  if (bid0 < 1250) {
    int e = bid0 * 256 + t;
    if (e < EE) atomicAdd(&deg[dst[e]], 1);
    if (e < NN) {
      int k = 0;
      #pragma unroll
      for (int j = 0; j < KK; j++) if (s[e * KK + j] > 0.5f) k = j;
      fid[e] = k;
    }
    return;
  }
  int bid = bid0 - 1250;
  if (bid < 96) {
    int l = bid >> 5, rem = bid & 31;
    int kb = rem >> 2, nb = rem & 3;
    int k0 = kb * 64, n0 = nb * 64;
    __shared__ float tile[64][65];
    const float* Wl = (k0 < 256) ? (Wi + (size_t)l * 65536 + (size_t)k0 * 256)
                                 : (Wo + (size_t)l * 65536 + (size_t)(k0 - 256) * 256);
    #pragma unroll
    for (int p = 0; p < 4; p++) {
      int ks = p * 16 + (t >> 4);
      int n  = (t & 15) * 4;
      float4 v = *(const float4*)&Wl[(size_t)ks * 256 + n0 + n];
      tile[ks][n] = v.x; tile[ks][n + 1] = v.y; tile[ks][n + 2] = v.z; tile[ks][n + 3] = v.w;
    }
    __syncthreads();
    ushort_t* BTl = BT + (size_t)l * 256 * 1024;
    #pragma unroll
    for (int p = 0; p < 2; p++) {
      int n  = p * 32 + (t >> 3);
      int kk = (t & 7) * 8;
      ushort_t hi[8], lo[8];
      #pragma unroll
      for (int j = 0; j < 8; j++) {
        float v = tile[kk + j][n];
        hi[j] = f2bf(v);
        lo[j] = f2bf(v - bf2f(hi[j]));
      }
      *(s8v*)&BTl[(size_t)(n0 + n) * 1024 + k0 + kk]       = *(const s8v*)hi;
      *(s8v*)&BTl[(size_t)(n0 + n) * 1024 + 512 + k0 + kk] = *(const s8v*)lo;
    }
  } else if (bid < 224) {
    int idx = (bid - 96) * 256 + t;   // n*128 + k
    int n = idx >> 7, k = idx & 127;
    int ks = k & 63;
    float v = 0.f;
    if (ks < DINF) v = Wi0[ks * 256 + n];
    else if (ks < 2 * DINF) v = Wo0[(ks - DINF) * 256 + n];
    ushort_t hi = f2bf(v);
    BT0[idx] = (k < 64) ? hi : f2bf(v - bf2f(hi));
  } else {
    // regloss partials over |Wo0| + |b_out0| + |Wo| + |b_out|
    int rb = bid - 224;               // 0..63
    int tid = rb * 256 + t;
    int stride = 64 * 256;
    float sum = 0.f;
    for (int i = tid; i < DINF * DD; i += stride)          sum += fabsf(Wo0[i]);
    for (int i = tid; i < DD; i += stride)                 sum += fabsf(b_out0[i]);
    for (int i = tid; i < (LL - 1) * DD * DD; i += stride) sum += fabsf(Wo[i]);
    for (int i = tid; i < (LL - 1) * DD; i += stride)      sum += fabsf(b_out[i]);
    __shared__ float red[8];
    float2 ss = block_reduce2(sum, 0.f, red);
    if (t == 0) partials[rb] = ss.x;
  }
}

// ---------------- prefix scan phase 1: per-chunk sums + dinv ----------------
__global__ __launch_bounds__(256) void chunk_kernel(const int* __restrict__ deg,
                                                    float* __restrict__ dinv,
                                                    int* __restrict__ chunk_sum) {
  int t = threadIdx.x;
  int n = blockIdx.x * 256 + t;
  int d = deg[n];
  dinv[n] = rsqrtf((float)max(d, 1));
  __shared__ int red[4];
  int v = d;
  #pragma unroll
  for (int off = 32; off > 0; off >>= 1) v += __shfl_down(v, off);
  if ((t & 63) == 0) red[t >> 6] = v;
  __syncthreads();
  if (t == 0) chunk_sum[blockIdx.x] = red[0] + red[1] + red[2] + red[3];
}

// ---------------- phase 2: chunk scan (redundant per block) + node scan ----------------
__global__ __launch_bounds__(256) void rowptr_kernel(const int* __restrict__ deg,
                                                     const int* __restrict__ chunk_sum,
                                                     int* __restrict__ row_ptr,
                                                     int* __restrict__ cursor) {
  int t = threadIdx.x;
  __shared__ int coff_s;
  __shared__ int wsum[4];
  if (t < 64) {                       // wave 0 re-scans the 40 chunk sums (160 B)
    int dd2 = (t < NN / 256) ? chunk_sum[t] : 0;
    int vv = dd2;
    #pragma unroll
    for (int off = 1; off < 64; off <<= 1) {
      int u = __shfl_up(vv, off);
      if (t >= off) vv += u;
    }
    if (t == (int)blockIdx.x) coff_s = vv - dd2;     // exclusive offset of my chunk
  }
  if (blockIdx.x == 0 && t == 64) row_ptr[NN] = EE;
  int lane = t & 63;
  int wid  = t >> 6;
  int n = blockIdx.x * 256 + t;
  int d = deg[n];
  int v = d;
  #pragma unroll
  for (int off = 1; off < 64; off <<= 1) {
    int u = __shfl_up(v, off);
    if (lane >= off) v += u;
  }
  if (lane == 63) wsum[wid] = v;
  __syncthreads();
  int woff = 0;
  #pragma unroll
  for (int p = 0; p < 4; p++) woff += (p < wid) ? wsum[p] : 0;
  int rp = coff_s + woff + (v - d);
  row_ptr[n] = rp;
  cursor[n]  = rp;
}

// ---------------- bucket edges into CSR by dst (packed int2) ----------------
__global__ __launch_bounds__(256) void bucket_kernel(const int* __restrict__ src,
                                                     const int* __restrict__ dst,
                                                     const int* __restrict__ mask,
                                                     const float* __restrict__ dinv,
                                                     int* __restrict__ cursor,
                                                     int2* __restrict__ epk) {
  int e = blockIdx.x * 256 + threadIdx.x;
  if (e >= EE) return;
  int sn = src[e], dn = dst[e];
  int p = atomicAdd(&cursor[dn], 1);
  epk[p] = make_int2(sn | (mask[e] ? (int)0x80000000 : 0),
                     __float_as_int(dinv[sn] * dinv[dn]));
}

// ---------------- layer-0 aggregation: wave-per-node, 8 edges in flight ----------------
__global__ __launch_bounds__(256) void agg0_kernel(const float* __restrict__ x,
                                                   const int2* __restrict__ epk,
                                                   const int* __restrict__ row_ptr,
                                                   ushort_t* __restrict__ agg0b) {
  int n = blockIdx.x * 4 + (threadIdx.x >> 6);
  int lane = threadIdx.x & 63;
  int half = lane >> 5;
  int ch = lane & 31;
  int chc = (ch < DINF) ? ch : 0;      // clamped safe address; unused lanes never write
  int e0 = row_ptr[n], e1 = row_ptr[n + 1];
  float accI = 0.f, accO = 0.f;
  for (int c0 = e0; c0 < e1; c0 += 64) {
    int cnt = min(64, e1 - c0);
    int2 my = (lane < cnt) ? epk[c0 + lane] : make_int2(0, 0);
    int i = half;
    for (; i + 6 < cnt; i += 8) {       // this half handles i, i+2, i+4, i+6
      unsigned u[4]; float w[4], v[4];
      #pragma unroll
      for (int j = 0; j < 4; j++) {
        u[j] = (unsigned)__shfl(my.x, i + 2 * j);
        w[j] = __int_as_float(__shfl(my.y, i + 2 * j));
      }
      #pragma unroll
      for (int j = 0; j < 4; j++)
        v[j] = x[(size_t)(u[j] & 0x7fffffffu) * DINF + chc];
      #pragma unroll
      for (int j = 0; j < 4; j++) {
        float wI = (u[j] >> 31) ? w[j] : 0.f;  float wO = w[j] - wI;
        accI = fmaf(v[j], wI, accI); accO = fmaf(v[j], wO, accO);
      }
    }
    for (; i < cnt; i += 2) {
      unsigned u = (unsigned)__shfl(my.x, i);
      float w = __int_as_float(__shfl(my.y, i));
      float v = x[(size_t)(u & 0x7fffffffu) * DINF + chc];
      float wI = (u >> 31) ? w : 0.f;  float wO = w - wI;
      accI = fmaf(v, wI, accI); accO = fmaf(v, wO, accO);
    }
  }
  accI += __shfl_xor(accI, 32);
  accO += __shfl_xor(accO, 32);
  if (half == 0) {
    if (ch < DINF) {
      agg0b[(size_t)n * 64 + ch]        = f2bf(accI);
      agg0b[(size_t)n * 64 + DINF + ch] = f2bf(accO);
    } else {
      int k = 2 * DINF + (ch - DINF) * 2;
      agg0b[(size_t)n * 64 + k] = 0;
      agg0b[(size_t)n * 64 + k + 1] = 0;
    }
  }
}

// ---------------- layer 1-3 aggregation: wave-per-node, scalar metadata, 8 edges in flight ----------------
__global__ __launch_bounds__(256) void agg_kernel(const ushort_t* __restrict__ h,
                                                  const int2* __restrict__ epk,
                                                  const int* __restrict__ row_ptr,
                                                  ushort_t* __restrict__ agg2b) {
  int n = blockIdx.x * 4 + (threadIdx.x >> 6);
  int lane = threadIdx.x & 63;
  int coff = lane * 4;
  int e0 = __builtin_amdgcn_readfirstlane(row_ptr[n]);
  int e1 = __builtin_amdgcn_readfirstlane(row_ptr[n + 1]);
  float aI0 = 0.f, aI1 = 0.f, aI2 = 0.f, aI3 = 0.f;
  float aO0 = 0.f, aO1 = 0.f, aO2 = 0.f, aO3 = 0.f;
  int i = e0;
  for (; i + 8 <= e1; i += 8) {
    int2 e[8];
    #pragma unroll
    for (int j = 0; j < 8; j++) e[j] = epk[i + j];
    ushort4 v[8];
    #pragma unroll
    for (int j = 0; j < 8; j++)
      v[j] = *(const ushort4*)&h[(size_t)(unsigned)(e[j].x & 0x7fffffff) * 256u + coff];
    #pragma unroll
    for (int j = 0; j < 8; j++) {
      float w = __int_as_float(e[j].y);
      float wI = (e[j].x < 0) ? w : 0.f;  float wO = w - wI;
      float f;
      f = bf2f(v[j].x); aI0 = fmaf(f, wI, aI0); aO0 = fmaf(f, wO, aO0);
      f = bf2f(v[j].y); aI1 = fmaf(f, wI, aI1); aO1 = fmaf(f, wO, aO1);
      f = bf2f(v[j].z); aI2 = fmaf(f, wI, aI2); aO2 = fmaf(f, wO, aO2);
      f = bf2f(v[j].w); aI3 = fmaf(f, wI, aI3); aO3 = fmaf(f, wO, aO3);
    }
  }
  for (; i < e1; i++) {
    int2 e = epk[i];
    ushort4 v = *(const ushort4*)&h[(size_t)(unsigned)(e.x & 0x7fffffff) * 256u + coff];
    float w = __int_as_float(e.y);
    float wI = (e.x < 0) ? w : 0.f;  float wO = w - wI;
    float f;
    f = bf2f(v.x); aI0 = fmaf(f, wI, aI0); aO0 = fmaf(f, wO, aO0);
    f = bf2f(v.y); aI1 = fmaf(f, wI, aI1); aO1 = fmaf(f, wO, aO1);
    f = bf2f(v.z); aI2 = fmaf(f, wI, aI2); aO2 = fmaf(f, wO, aO2);
    f = bf2f(v.w); aI3 = fmaf(f, wI, aI3); aO3 = fmaf(f, wO, aO3);
  }
  ushort_t* row = &agg2b[(size_t)n * 512];
  ushort4 pI, pO;
  pI.x = f2bf(aI0); pI.y = f2bf(aI1); pI.z = f2bf(aI2); pI.w = f2bf(aI3);
  pO.x = f2bf(aO0); pO.y = f2bf(aO1); pO.z = f2bf(aO2); pO.w = f2bf(aO3);
  *(ushort4*)&row[coff]       = pI;
  *(ushort4*)&row[256 + coff] = pO;
}

// ---------------- MFMA GEMM v2: global_load_lds staging, swizzled linear LDS,
// 4 waves x (32 rows x 64 cols) = 2 row-frags x 4 col-frags per wave.
// Per K-step per wave: 12 ds_read_b128 : 16 MFMA (was 18:16 + 9 ds_write).
// LDS 37 KB -> 4 blocks/CU. Swizzle: source-addr XOR ((row&7)<<4) + read XOR (rule-21 b).
template <int KB>
__global__ __launch_bounds__(256, 4) void gemm_mfma_ln(const ushort_t* __restrict__ A,
                                                       const ushort_t* __restrict__ BT,
                                                       const float* __restrict__ bi,
                                                       const float* __restrict__ bo,
                                                       const float* __restrict__ g,
                                                       const float* __restrict__ bb,
                                                       ushort_t* __restrict__ hout) {
  constexpr int AK = KB / 2;               // A row length (shorts)
  constexpr int ABR = AK * 2;              // A row bytes
  constexpr int BBR = KB * 2;              // BT row bytes
  __shared__ __align__(16) ushort_t As[32 * 64];
  __shared__ __align__(16) ushort_t Bs[256 * 64];
  __shared__ float redS[32][4];
  __shared__ float redQ[32][4];
  int t = threadIdx.x;
  int m0 = blockIdx.x * 32;
  int w = t >> 6;
  int lane = t & 63;
  int q = lane >> 4, n16 = lane & 15;
  int sx = (n16 & 7) << 3;                 // read-side swizzle (short units)
  f4v acc[2][4];
  #pragma unroll
  for (int rt = 0; rt < 2; rt++)
    #pragma unroll
    for (int ct = 0; ct < 4; ct++) acc[rt][ct] = (f4v){0.f, 0.f, 0.f, 0.f};

  // staging geometry (constant per lane across the K loop)
  int srow   = lane >> 3;                  // row within this wave's 8-row group
  int sobyte = (lane & 7) * 16;            // 16B slot within the 128B chunk
  int arow   = w * 8 + srow;               // As row staged by this lane
  size_t a_base = (size_t)(m0 + arow) * ABR + (size_t)(sobyte ^ ((arow & 7) << 4));
  char* as_dst = (char*)As + w * 1024;     // wave-uniform LDS bases
  char* bs_dst = (char*)Bs + w * 8192;

  for (int k0 = 0; k0 < KB; k0 += 64) {
    __syncthreads();                       // previous tile fully consumed
    gld16((const char*)A + a_base + (size_t)((k0 & (AK - 1)) * 2), as_dst);
    #pragma unroll
    for (int j = 0; j < 8; j++) {
      int brow = w * 64 + j * 8 + srow;
      gld16((const char*)BT + (size_t)brow * BBR + (size_t)(k0 * 2)
                + (size_t)(sobyte ^ ((brow & 7) << 4)),
            bs_dst + j * 1024);
    }
    asm volatile("s_waitcnt vmcnt(0)" ::: "memory");
    __syncthreads();                       // tile ready
    #pragma unroll
    for (int kk = 0; kk < 2; kk++) {
      int ko = (kk * 32 + q * 8) ^ sx;
      s8v af0 = *(const s8v*)&As[n16 * 64 + ko];
      s8v af1 = *(const s8v*)&As[(16 + n16) * 64 + ko];
      #pragma unroll
      for (int ct = 0; ct < 4; ct++) {
        s8v bf = *(const s8v*)&Bs[(w * 64 + ct * 16 + n16) * 64 + ko];
        acc[0][ct] = __builtin_amdgcn_mfma_f32_16x16x32_bf16(af0, bf, acc[0][ct], 0, 0, 0);
        acc[1][ct] = __builtin_amdgcn_mfma_f32_16x16x32_bf16(af1, bf, acc[1][ct], 0, 0, 0);
      }
    }
  }

  // epilogue: bias, row-LN across the 4 col-quarter waves, ReLU, bf16 store
  float biv[4], gv[4], bbv[4];
  #pragma unroll
  for (int ct = 0; ct < 4; ct++) {
    int c = w * 64 + ct * 16 + n16;
    biv[ct] = bi[c] + bo[c];
    gv[ct]  = g[c];
    bbv[ct] = bb[c];
  }
  #pragma unroll
  for (int rt = 0; rt < 2; rt++)
    #pragma unroll
    for (int rg = 0; rg < 4; rg++) {
      float s = 0.f, ss = 0.f;
      #pragma unroll
      for (int ct = 0; ct < 4; ct++) {
        float v = acc[rt][ct][rg] + biv[ct];
        s += v; ss += v * v;
      }
      #pragma unroll
      for (int off = 1; off < 16; off <<= 1) {
        s  += __shfl_xor(s, off);
        ss += __shfl_xor(ss, off);
      }
      if (n16 == 0) {
        int row = rt * 16 + q * 4 + rg;
        redS[row][w] = s;
        redQ[row][w] = ss;
      }
    }
  __syncthreads();
  #pragma unroll
  for (int rt = 0; rt < 2; rt++)
    #pragma unroll
    for (int rg = 0; rg < 4; rg++) {
      int row = rt * 16 + q * 4 + rg;
      float mean = (redS[row][0] + redS[row][1] + redS[row][2] + redS[row][3]) * (1.f / 256.f);
      float var  = (redQ[row][0] + redQ[row][1] + redQ[row][2] + redQ[row][3]) * (1.f / 256.f)
                   - mean * mean;
      float rs = rsqrtf(fmaxf(var, 0.f) + LNEPS);
      #pragma unroll
      for (int ct = 0; ct < 4; ct++) {
        float v = acc[rt][ct][rg] + biv[ct];
        float o = fmaxf((v - mean) * rs * gv[ct] + bbv[ct], 0.f);
        hout[(size_t)(m0 + row) * 256 + w * 64 + ct * 16 + n16] = f2bf(o);
      }
    }
}

// ---------------- fragment pooling + LN + mask; extra block finalizes regloss ----------------
__global__ __launch_bounds__(256) void frag_pool_kernel(const ushort_t* __restrict__ h,
                                                        const int* __restrict__ fid,
                                                        const float* __restrict__ g,
                                                        const float* __restrict__ bb,
                                                        const float* __restrict__ partials,
                                                        float* __restrict__ out_emb,
                                                        float* __restrict__ out_mask,
                                                        float* __restrict__ out_reg) {
  int d = threadIdx.x;
  if (blockIdx.x == BGR * KK) {       // regloss final: sum 64 partials
    if (d < 64) {
      float sv = partials[d];
      #pragma unroll
      for (int off = 32; off > 0; off >>= 1) sv += __shfl_down(sv, off);
      if (d == 0) out_reg[0] = sv;
    }
    return;
  }
  int b = blockIdx.x >> 4;
  int k = blockIdx.x & 15;
  __shared__ int list[NPG];
  __shared__ int cnt;
  __shared__ float red[8];
  if (d == 0) cnt = 0;
  __syncthreads();
  int base = b * NPG;
  if (d < NPG) {
    if (fid[base + d] == k) { int p = atomicAdd(&cnt, 1); list[p] = d; }
  }
  __syncthreads();
  int c = cnt;
  float acc = 0.f;
  int i = 0;
  for (; i + 4 <= c; i += 4) {
    int l0 = list[i], l1 = list[i + 1], l2 = list[i + 2], l3 = list[i + 3];
    float a0 = bf2f(h[(size_t)(base + l0) * 256 + d]);
    float a1 = bf2f(h[(size_t)(base + l1) * 256 + d]);
    float a2 = bf2f(h[(size_t)(base + l2) * 256 + d]);
    float a3 = bf2f(h[(size_t)(base + l3) * 256 + d]);
    acc += (a0 + a1) + (a2 + a3);
  }
  for (; i < c; i++) {
    acc += bf2f(h[(size_t)(base + list[i]) * 256 + d]);
  }
  float2 ss = block_reduce2(acc, acc * acc, red);
  float mean = ss.x * (1.f / 256.f);
  float var  = ss.y * (1.f / 256.f) - mean * mean;
  float o = (acc - mean) * rsqrtf(fmaxf(var, 0.f) + LNEPS) * g[d] + bb[d];
  out_emb[((size_t)b * KK + k) * 256 + d] = o;
  if (d == 0) out_mask[b * KK + k] = (c > 0) ? 1.f : 0.f;
}

// ---------------- launch ----------------
static inline size_t align256(size_t x) { return (x + 255) & ~(size_t)255; }

extern "C" void kernel_launch(void* const* d_in, const int* in_sizes, int n_in,
                              void* d_out, int out_size, void* d_ws, size_t ws_size,
                              hipStream_t stream) {
  const float* x      = (const float*)d_in[0];
  const int*   ei     = (const int*)d_in[1];
  const int*   mask   = (const int*)d_in[2];
  const float* s      = (const float*)d_in[3];
  const float* W_in0  = (const float*)d_in[5];
  const float* W_out0 = (const float*)d_in[6];
  const float* b_in0  = (const float*)d_in[7];
  const float* b_out0 = (const float*)d_in[8];
  const float* W_in   = (const float*)d_in[9];
  const float* W_out  = (const float*)d_in[10];
  const float* b_in   = (const float*)d_in[11];
  const float* b_out  = (const float*)d_in[12];
  const float* ln_g   = (const float*)d_in[13];
  const float* ln_b   = (const float*)d_in[14];
  const float* fbn_g  = (const float*)d_in[15];
  const float* fbn_b  = (const float*)d_in[16];

  const int* src = ei;
  const int* dst = ei + EE;

  char* w = (char*)d_ws;
  int*      deg     = (int*)w;      w += align256((size_t)NN * 4);
  int*      row_ptr = (int*)w;      w += align256((size_t)(NN + 1) * 4);
  int*      cursor  = (int*)w;      w += align256((size_t)NN * 4);
  float*    dinv    = (float*)w;    w += align256((size_t)NN * 4);
  int*      fid     = (int*)w;      w += align256((size_t)NN * 4);
  int*      chunks  = (int*)w;      w += align256((size_t)(NN / 256) * 4);
  float*    rlpart  = (float*)w;    w += align256((size_t)64 * 4);
  int2*     epk     = (int2*)w;     w += align256((size_t)EE * 8);
  ushort_t* BT0     = (ushort_t*)w; w += align256((size_t)256 * 128 * 2);
  ushort_t* BTw     = (ushort_t*)w; w += align256((size_t)3 * 256 * 1024 * 2);
  ushort_t* agg0b   = (ushort_t*)w; w += align256((size_t)NN * 64 * 2);
  ushort_t* agg2b   = (ushort_t*)w; w += align256((size_t)NN * 512 * 2);
  ushort_t* hbuf    = (ushort_t*)w; w += align256((size_t)NN * 256 * 2);

  float* out_emb  = (float*)d_out;
  float* out_mask = out_emb + (size_t)BGR * KK * DD;
  float* out_reg  = out_emb + (size_t)out_size - 1;

  hipMemsetAsync(deg, 0, (size_t)NN * 4, stream);
  setup_kernel<<<1250 + 288, 256, 0, stream>>>(dst, s, W_in, W_out, W_in0, W_out0,
                                               b_out0, b_out, deg, fid, BTw, BT0, rlpart);
  chunk_kernel<<<NN / 256, 256, 0, stream>>>(deg, dinv, chunks);
  rowptr_kernel<<<NN / 256, 256, 0, stream>>>(deg, chunks, row_ptr, cursor);
  bucket_kernel<<<(EE + 255) / 256, 256, 0, stream>>>(src, dst, mask, dinv, cursor, epk);

  // layer 0: aggregate x, then MFMA transform + LN + ReLU
  agg0_kernel<<<NN / 4, 256, 0, stream>>>(x, epk, row_ptr, agg0b);
  gemm_mfma_ln<128><<<NN / 32, 256, 0, stream>>>(agg0b, BT0, b_in0, b_out0, ln_g, ln_b, hbuf);
  // layers 1..3
  for (int l = 0; l < LL - 1; l++) {
    agg_kernel<<<NN / 4, 256, 0, stream>>>(hbuf, epk, row_ptr, agg2b);
    gemm_mfma_ln<1024><<<NN / 32, 256, 0, stream>>>(agg2b, BTw + (size_t)l * 256 * 1024,
                                                    b_in + l * 256, b_out + l * 256,
                                                    ln_g + (l + 1) * 256, ln_b + (l + 1) * 256,
                                                    hbuf);
  }

  frag_pool_kernel<<<BGR * KK + 1, 256, 0, stream>>>(hbuf, fid, fbn_g, fbn_b, rlpart,
                                                     out_emb, out_mask, out_reg);
}